// Round 7
// baseline (27.095 us; speedup 1.0000x reference)
//
#include <hip/hip_runtime.h>
#include <math.h>

#define TLEN 4096
#define LEVELS 4
#define CHANS 32
#define SLOPE 10.0f

__device__ __forceinline__ float clamp30(float v) {
    return __builtin_amdgcn_fmed3f(v, -30.f, 30.f);
}

// d = hi * (sigmoid(S*(hi-b)) + sigmoid(-S*(hi+b)))
//   = hi * (2 + ea + eb) / ((1+ea)*(1+eb)),  ea=exp(-S*(hi-b)), eb=exp(S*(hi+b))
// clamp exp args to +-30 (fmed3) so ea*eb stays finite -> no inf*0 NaN.
__device__ __forceinline__ float sgate(float hi, float b) {
    const float ea = __expf(clamp30(-SLOPE * (hi - b)));
    const float eb = __expf(clamp30( SLOPE * (hi + b)));
    return hi * (2.f + ea + eb) * __builtin_amdgcn_rcpf((1.f + ea) * (1.f + eb));
}

// One full 4-level row decomposition. `in` = 18 input floats already in
// registers (16 owned + 2 halo). Uses bufA (2048, de-interleaved halves)
// and bufB (1024). Caller barriers between rows.
__device__ __forceinline__ void process_row(
    const float (&in)[18], const int c, const int tid,
    const float* __restrict__ h_lo, const float* __restrict__ bias,
    float* __restrict__ orow, float* bufA, float* bufB)
{
    const float4 k0v = ((const float4*)h_lo)[c * LEVELS + 0];
    const float4 k1v = ((const float4*)h_lo)[c * LEVELS + 1];
    const float4 k2v = ((const float4*)h_lo)[c * LEVELS + 2];
    const float4 k3v = ((const float4*)h_lo)[c * LEVELS + 3];
    const float b0 = bias[c * LEVELS + 0];
    const float b1 = bias[c * LEVELS + 1];
    const float b2 = bias[c * LEVELS + 2];
    const float b3 = bias[c * LEVELS + 3];

    // ---- Level 1: regs -> lo in bufA (split halves), d1 -> orow[2048..4096)
    {
        float lo[8], dd[8];
        #pragma unroll
        for (int j = 0; j < 8; ++j) {
            const float a0 = in[2*j], a1 = in[2*j+1], a2 = in[2*j+2], a3 = in[2*j+3];
            lo[j] = a0*k0v.x + a1*k0v.y + a2*k0v.z + a3*k0v.w;
            const float hi = a0*k0v.w - a1*k0v.z + a2*k0v.y - a3*k0v.x;
            dd[j] = sgate(hi, b0);
        }
        ((float4*)bufA)[tid]          = make_float4(lo[0], lo[1], lo[2], lo[3]);
        ((float4*)(bufA + 1024))[tid] = make_float4(lo[4], lo[5], lo[6], lo[7]);
        float4* o4 = (float4*)(orow + 2048);
        o4[2*tid]   = make_float4(dd[0], dd[1], dd[2], dd[3]);
        o4[2*tid+1] = make_float4(dd[4], dd[5], dd[6], dd[7]);
    }
    __syncthreads();

    // ---- Level 2: bufA (de-interleaved) -> lo in bufB, d2 -> orow[1024..2048)
    {
        float t[10];
        const float4 v0 = ((const float4*)bufA)[tid];          // out1[8t..8t+3]
        const float4 v1 = ((const float4*)(bufA + 1024))[tid]; // out1[8t+4..8t+7]
        t[0] = v0.x; t[1] = v0.y; t[2] = v0.z; t[3] = v0.w;
        t[4] = v1.x; t[5] = v1.y; t[6] = v1.z; t[7] = v1.w;
        const float2 e = *(const float2*)(bufA + ((4 * (tid + 1)) & 1023)); // out1[8t+8..9]
        t[8] = e.x; t[9] = e.y;

        float lo[4], dd[4];
        #pragma unroll
        for (int j = 0; j < 4; ++j) {
            const float a0 = t[2*j], a1 = t[2*j+1], a2 = t[2*j+2], a3 = t[2*j+3];
            lo[j] = a0*k1v.x + a1*k1v.y + a2*k1v.z + a3*k1v.w;
            const float hi = a0*k1v.w - a1*k1v.z + a2*k1v.y - a3*k1v.x;
            dd[j] = sgate(hi, b1);
        }
        ((float4*)bufB)[tid] = make_float4(lo[0], lo[1], lo[2], lo[3]);
        ((float4*)(orow + 1024))[tid] = make_float4(dd[0], dd[1], dd[2], dd[3]);
    }
    __syncthreads();

    // ---- Level 3: bufB[0..1024) -> lo in bufA[0..512), d3 -> orow[512..1024)
    {
        float t[6];
        const float4 v = ((const float4*)bufB)[tid];
        t[0] = v.x; t[1] = v.y; t[2] = v.z; t[3] = v.w;
        const float2 e = *(const float2*)(bufB + ((4 * tid + 4) & 1023));
        t[4] = e.x; t[5] = e.y;

        float lo[2], dd[2];
        #pragma unroll
        for (int j = 0; j < 2; ++j) {
            const float a0 = t[2*j], a1 = t[2*j+1], a2 = t[2*j+2], a3 = t[2*j+3];
            lo[j] = a0*k2v.x + a1*k2v.y + a2*k2v.z + a3*k2v.w;
            const float hi = a0*k2v.w - a1*k2v.z + a2*k2v.y - a3*k2v.x;
            dd[j] = sgate(hi, b2);
        }
        ((float2*)bufA)[tid] = make_float2(lo[0], lo[1]);
        ((float2*)(orow + 512))[tid] = make_float2(dd[0], dd[1]);
    }
    __syncthreads();

    // ---- Level 4: bufA[0..512) -> yl in orow[0..256), d4 -> orow[256..512)
    {
        const float2 a01 = *(const float2*)(bufA + 2 * tid);
        const float2 e   = *(const float2*)(bufA + ((2 * tid + 2) & 511));
        const float a0 = a01.x, a1 = a01.y, a2 = e.x, a3 = e.y;
        const float lo = a0*k3v.x + a1*k3v.y + a2*k3v.z + a3*k3v.w;
        const float hi = a0*k3v.w - a1*k3v.z + a2*k3v.y - a3*k3v.x;
        orow[tid]       = lo;
        orow[256 + tid] = sgate(hi, b3);
    }
}

__global__ __launch_bounds__(256) void lwpt_kernel(
    const float* __restrict__ x, const float* __restrict__ h_lo,
    const float* __restrict__ bias, float* __restrict__ out)
{
    __shared__ float bufA[2048];
    __shared__ float bufB[1024];

    const int tid = threadIdx.x;
    const int bc0 = blockIdx.x * 2;          // rows bc0 and bc0+1

    // ---- Hoisted loads: BOTH rows' inputs issued before any compute.
    // Row B's loads complete under row A's compute -> continuous read stream.
    float inA[18], inB[18];
    {
        const float* xr0 = x + (size_t)bc0 * TLEN;
        const float4* x40 = (const float4*)xr0;
        const float* xr1 = xr0 + TLEN;
        const float4* x41 = (const float4*)xr1;
        #pragma unroll
        for (int k = 0; k < 4; ++k) {
            const float4 v = x40[4 * tid + k];
            inA[4*k+0] = v.x; inA[4*k+1] = v.y; inA[4*k+2] = v.z; inA[4*k+3] = v.w;
        }
        const float2 e0 = *(const float2*)(xr0 + ((16 * tid + 16) & (TLEN - 1)));
        inA[16] = e0.x; inA[17] = e0.y;
        #pragma unroll
        for (int k = 0; k < 4; ++k) {
            const float4 v = x41[4 * tid + k];
            inB[4*k+0] = v.x; inB[4*k+1] = v.y; inB[4*k+2] = v.z; inB[4*k+3] = v.w;
        }
        const float2 e1 = *(const float2*)(xr1 + ((16 * tid + 16) & (TLEN - 1)));
        inB[16] = e1.x; inB[17] = e1.y;
    }

    const int c0 = bc0 & (CHANS - 1);
    process_row(inA, c0, tid, h_lo, bias, out + (size_t)bc0 * TLEN, bufA, bufB);

    __syncthreads();   // row A's level-4 bufA reads done before row B rewrites

    const int c1 = (bc0 + 1) & (CHANS - 1);
    process_row(inB, c1, tid, h_lo, bias, out + (size_t)(bc0 + 1) * TLEN, bufA, bufB);
}

extern "C" void kernel_launch(void* const* d_in, const int* in_sizes, int n_in,
                              void* d_out, int out_size, void* d_ws, size_t ws_size,
                              hipStream_t stream) {
    const float* x    = (const float*)d_in[0];
    const float* h_lo = (const float*)d_in[1];
    const float* bias = (const float*)d_in[2];
    float* out = (float*)d_out;

    dim3 grid(128 * CHANS / 2);
    dim3 block(256);
    lwpt_kernel<<<grid, block, 0, stream>>>(x, h_lo, bias, out);
}